// Round 7
// baseline (2837.254 us; speedup 1.0000x reference)
//
#include <hip/hip_runtime.h>
#include <hip/hip_bf16.h>
#include <math.h>

// DRAW: B=512, C=1, H=W=128, RS=WS=12, L=128, HID=512, T=16
#define BATCH 512
#define HID 512
#define LAT 128
#define TSTEPS 16
#define IMG 16384      // 128*128
#define ENC_IN 800     // 2*12*12 + 512
#define GATES 2048     // 4*HID

// bf16x3 split-GEMM geometry. A and W stored [hi | lo]; virtual K = 3*SEC:
// hi*hi, hi*lo, lo*hi (lo*lo dropped, ~2^-16 relative).
// A_enc row: [glimpse 288 | h_dec 512 | h_enc 512 | pad 32] = 1344
// A_dec row: [z 128 | h_dec 512] = 640
#define SEC_E 1344
#define SEC_D 640

typedef __attribute__((ext_vector_type(8))) short short8;
typedef __attribute__((ext_vector_type(4))) float f32x4;

// ---------------------------------------------------------------- helpers
__device__ __forceinline__ void gload16(const void* g, void* l) {
    __builtin_amdgcn_global_load_lds((const __attribute__((address_space(1))) unsigned int*)g,
                                     (__attribute__((address_space(3))) unsigned int*)l, 16, 0, 0);
}

__device__ __forceinline__ void bsplit(float v, unsigned short& hi, unsigned short& lo) {
    unsigned u = __float_as_uint(v);
    unsigned uh = (u + (0x7FFFu + ((u >> 16) & 1u))) & 0xFFFF0000u;   // RNE bf16
    hi = (unsigned short)(uh >> 16);
    float r = v - __uint_as_float(uh);                                 // exact residual
    unsigned ur = __float_as_uint(r);
    unsigned ul = (ur + (0x7FFFu + ((ur >> 16) & 1u))) & 0xFFFF0000u;
    lo = (unsigned short)(ul >> 16);
}

// ---------------------------------------------------------------- init
__global__ __launch_bounds__(256) void init_canvas(float* __restrict__ canvas,
                                                   const float* __restrict__ ci) {
    int idx = blockIdx.x * 256 + threadIdx.x;
    canvas[idx] = ci[idx & (IMG - 1)];
}

__global__ __launch_bounds__(256) void init_state(float* __restrict__ he, float* __restrict__ ce,
                                                  float* __restrict__ hd, float* __restrict__ cd,
                                                  const float* __restrict__ hei,
                                                  const float* __restrict__ hdi,
                                                  unsigned short* __restrict__ A_enc,
                                                  unsigned short* __restrict__ A_dec) {
    int idx = blockIdx.x * 256 + threadIdx.x;   // B*HID
    int b = idx >> 9, u = idx & 511;
    float ve = hei[u], vd = hdi[u];
    he[idx] = ve;
    hd[idx] = vd;
    ce[idx] = 0.f;
    cd[idx] = 0.f;
    unsigned short hi, lo;
    bsplit(ve, hi, lo);
    size_t be = (size_t)b * 2 * SEC_E;
    A_enc[be + 800 + u] = hi;
    A_enc[be + SEC_E + 800 + u] = lo;
    bsplit(vd, hi, lo);
    size_t bd = (size_t)b * 2 * SEC_D;
    A_dec[bd + 128 + u] = hi;
    A_dec[bd + SEC_D + 128 + u] = lo;
}

// ---------------------------------------------------------------- weight preps (once/launch)
__global__ __launch_bounds__(256) void prep_wsplit(const float* __restrict__ W1, int K1,
                                                   const float* __restrict__ W2, int K2,
                                                   unsigned short* __restrict__ out, int SEC) {
    int kk = blockIdx.x * 256 + threadIdx.x;
    int n = blockIdx.y;
    if (kk >= SEC) return;
    float v = 0.f;
    if (kk < K1) v = W1[(size_t)n * K1 + kk];
    else if (kk < K1 + K2) v = W2[(size_t)n * K2 + (kk - K1)];
    unsigned short hi, lo;
    bsplit(v, hi, lo);
    size_t base = (size_t)n * 2 * SEC;
    out[base + kk] = hi;
    out[base + SEC + kk] = lo;
}

// W_samp (256x512) -> WsT (512x256)
__global__ __launch_bounds__(256) void prep_wsampT(const float* __restrict__ W,
                                                   float* __restrict__ WT) {
    int i = blockIdx.x * 256 + threadIdx.x;   // 131072
    int o = i >> 9, k = i & 511;
    WT[k * 256 + o] = W[o * 512 + k];
}

// ---------------------------------------------------------------- bf16x3 MFMA GEMM
__global__ __launch_bounds__(256) void gemm_bf16x3(const unsigned short* __restrict__ Au,
                                                   const unsigned short* __restrict__ Wu,
                                                   float* __restrict__ C, int SEC,
                                                   int ktb0, int kte0, int ktb1, int kte1) {
    __shared__ __align__(16) char lds[2][16384];   // per buf: A [0,8192), B [8192,16384)
    const __bf16* A = (const __bf16*)Au;
    const __bf16* Wt = (const __bf16*)Wu;
    const int ld = 2 * SEC;
    const int tid = threadIdx.x;
    const int z = blockIdx.z;
    const int bm = blockIdx.x * 64;
    const int bn = blockIdx.y * 64;
    const int ktb = z ? ktb1 : ktb0;
    const int kte = z ? kte1 : kte0;

    const int row0 = tid >> 3, c0 = tid & 7;
    const size_t ga0 = (size_t)(bm + row0) * ld + (size_t)((c0 ^ (row0 & 7)) * 8);
    const size_t ga1 = ga0 + (size_t)32 * ld;
    const size_t gb0 = (size_t)(bn + row0) * ld + (size_t)((c0 ^ (row0 & 7)) * 8);
    const size_t gb1 = gb0 + (size_t)32 * ld;
    const int lA0 = tid * 16, lA1 = (tid + 256) * 16;
    const int lB0 = 8192 + tid * 16, lB1 = 8192 + (tid + 256) * 16;

    const int lane = tid & 63, wv = tid >> 6;
    const int rA = wv * 16 + (lane & 15);
    const int chnk = (lane >> 4) ^ (lane & 7);
    const int byteA = rA * 128 + chnk * 16;
    const int byteB = 8192 + (lane & 15) * 128 + chnk * 16;

    f32x4 acc[4];
#pragma unroll
    for (int j = 0; j < 4; ++j) acc[j] = (f32x4){0.f, 0.f, 0.f, 0.f};

    auto STAGE = [&](int buf, int kt) {
        const int kw = kt * 64;
        const int ka = (kw >= SEC) ? (kw - SEC) : kw;            // A: hi,hi,lo
        const int kb = (kw >= 2 * SEC) ? (kw - 2 * SEC) : kw;    // W: hi,lo,hi
        const __bf16* a = A + ka;
        const __bf16* w = Wt + kb;
        char* l = &lds[buf][0];
        gload16(a + ga0, l + lA0);
        gload16(a + ga1, l + lA1);
        gload16(w + gb0, l + lB0);
        gload16(w + gb1, l + lB1);
    };

    STAGE(0, ktb);
    asm volatile("s_waitcnt vmcnt(0)" ::: "memory");
    __syncthreads();
    int buf = 0;
    for (int kt = ktb; kt < kte; ++kt) {
        if (kt + 1 < kte) STAGE(buf ^ 1, kt + 1);
        const char* base = &lds[buf][0];
        short8 a0 = *(const short8*)(base + byteA);
        short8 a1 = *(const short8*)(base + (byteA ^ 64));
#pragma unroll
        for (int j = 0; j < 4; ++j) {
            short8 b0 = *(const short8*)(base + (byteB + j * 2048));
            short8 b1 = *(const short8*)(base + ((byteB + j * 2048) ^ 64));
            acc[j] = __builtin_amdgcn_mfma_f32_16x16x32_bf16(a0, b0, acc[j], 0, 0, 0);
            acc[j] = __builtin_amdgcn_mfma_f32_16x16x32_bf16(a1, b1, acc[j], 0, 0, 0);
        }
        asm volatile("s_waitcnt vmcnt(0)" ::: "memory");
        __syncthreads();
        buf ^= 1;
    }
    float* Cz = C + (size_t)z * BATCH * GATES;
    const int crow = bm + wv * 16 + (lane >> 4) * 4;
    const int ccol = bn + (lane & 15);
#pragma unroll
    for (int j = 0; j < 4; ++j)
#pragma unroll
        for (int r = 0; r < 4; ++r)
            Cz[(size_t)(crow + r) * GATES + ccol + j * 16] = acc[j][r];
}

// ---------------------------------------------------------------- fused read (t=0 only)
__global__ __launch_bounds__(512, 4) void read_glimpse_fused(const float* __restrict__ x,
                                                             const float* __restrict__ canvas,
                                                             const float* __restrict__ h_dec,
                                                             const float* __restrict__ Wa,
                                                             const float* __restrict__ ba,
                                                             unsigned short* __restrict__ A_enc) {
    const int b = blockIdx.x, t = threadIdx.x;
    __shared__ float par[5];
    __shared__ float fx[12][132], fy[12][132];
    __shared__ float dn[24];
    __shared__ float tm[12][132], te[12][132];
    __shared__ __align__(16) float pbuf[8][12][128];
    float* red = &pbuf[0][0][0];
    const float* hb = h_dec + (size_t)b * HID;
#pragma unroll
    for (int j = 0; j < 5; ++j) red[j * 512 + t] = hb[t] * Wa[j * HID + t];
    __syncthreads();
    for (int o = 256; o > 0; o >>= 1) {
        if (t < o) {
#pragma unroll
            for (int j = 0; j < 5; ++j) red[j * 512 + t] += red[j * 512 + t + o];
        }
        __syncthreads();
    }
    if (t < 5) par[t] = red[t * 512] + ba[t];
    __syncthreads();
    const float gx = 129.f * (par[0] + 1.f) * 0.5f;
    const float gy = 129.f * (par[1] + 1.f) * 0.5f;
    const float var = expf(par[2]);
    const float strd = 127.f * expf(par[3]) / 11.f;
    const float iv = expf(par[4]);
#pragma unroll
    for (int rep = 0; rep < 6; ++rep) {
        int e = t + rep * 512;
        int mat = e / 1536;
        int rr = (e - mat * 1536) >> 7;
        int cc = e & 127;
        float ctr = (mat ? gy : gx) + ((float)rr + 0.5f - 6.f) * strd;
        float d = (float)cc - ctr;
        float v = expf(-(d * d) / (2.f * var));
        float (*dst)[132] = mat ? fy : fx;
        dst[rr][cc] = v;
    }
    __syncthreads();
    if (t < 24) {
        const float (*src)[132] = (t < 12) ? fx : fy;
        int rr = (t < 12) ? t : t - 12;
        float s = 0.f;
        for (int k = 0; k < 128; ++k) s += src[rr][k];
        dn[t] = fmaxf(s, 1e-8f);
    }
    __syncthreads();
#pragma unroll
    for (int rep = 0; rep < 6; ++rep) {
        int e = t + rep * 512;
        int mat = e / 1536;
        int rr = (e - mat * 1536) >> 7;
        int cc = e & 127;
        float (*dst)[132] = mat ? fy : fx;
        dst[rr][cc] /= dn[mat * 12 + rr];
    }
    __syncthreads();
    const int g = t >> 6, l = t & 63, c2 = l * 2;
    float2 am[12] = {}, ae[12] = {};
    const float* xb = x + (size_t)b * IMG;
    const float* cb = canvas + (size_t)b * IMG;
    for (int hh = g * 16; hh < g * 16 + 16; ++hh) {
        float2 xv = *(const float2*)(xb + hh * 128 + c2);
        float2 cv = *(const float2*)(cb + hh * 128 + c2);
        float2 xe;
        xe.x = xv.x - 1.f / (1.f + expf(-cv.x));
        xe.y = xv.y - 1.f / (1.f + expf(-cv.y));
#pragma unroll
        for (int i = 0; i < 12; ++i) {
            float f = fy[i][hh];
            am[i].x += f * xv.x;
            am[i].y += f * xv.y;
            ae[i].x += f * xe.x;
            ae[i].y += f * xe.y;
        }
    }
#pragma unroll
    for (int i = 0; i < 12; ++i) *(float2*)(&pbuf[g][i][c2]) = am[i];
    __syncthreads();
    for (int it = t; it < 1536; it += 512) {
        int ii = it >> 7, cc = it & 127;
        float s = 0.f;
#pragma unroll
        for (int k = 0; k < 8; ++k) s += pbuf[k][ii][cc];
        tm[ii][cc] = s;
    }
    __syncthreads();
#pragma unroll
    for (int i = 0; i < 12; ++i) *(float2*)(&pbuf[g][i][c2]) = ae[i];
    __syncthreads();
    for (int it = t; it < 1536; it += 512) {
        int ii = it >> 7, cc = it & 127;
        float s = 0.f;
#pragma unroll
        for (int k = 0; k < 8; ++k) s += pbuf[k][ii][cc];
        te[ii][cc] = s;
    }
    __syncthreads();
    unsigned short hi, lo;
    unsigned short* rb = A_enc + (size_t)b * 2 * SEC_E;
    if (t < 288) {
        int ch = (t >= 144) ? 1 : 0;
        int rem = t - ch * 144;
        int ii = rem / 12, jj = rem - ii * 12;
        const float* src = ch ? te[ii] : tm[ii];
        float s = 0.f;
        for (int w2 = 0; w2 < 128; ++w2) s += src[w2] * fx[jj][w2];
        bsplit(iv * s, hi, lo);
        rb[t] = hi;
        rb[SEC_E + t] = lo;
    }
    bsplit(hb[t], hi, lo);
    rb[288 + t] = hi;
    rb[SEC_E + 288 + t] = lo;
    if (t < 32) {
        rb[1312 + t] = 0;
        rb[SEC_E + 1312 + t] = 0;
    }
}

// ---------------------------------------------------------------- fused write(t) + read(t+1)
// Both phases use the same h_dec. canvas updated in-register then consumed.
__global__ __launch_bounds__(512, 2) void rw_canvas_fused(float* __restrict__ canvas,
                                                          const float* __restrict__ x,
                                                          const float* __restrict__ h_dec,
                                                          const float* __restrict__ Wwa,
                                                          const float* __restrict__ bwa,
                                                          const float* __restrict__ Wwr,
                                                          const float* __restrict__ bwr,
                                                          const float* __restrict__ Wra,
                                                          const float* __restrict__ bra,
                                                          unsigned short* __restrict__ A_enc) {
    const int b = blockIdx.x, t = threadIdx.x;
    __shared__ float hl[512];
    __shared__ float par[10];                      // 0..4 write attn, 5..9 read attn
    __shared__ float fxw[12][132], fyw[12][132], fxr[12][132], fyr[12][132];
    __shared__ float dn[48];
    __shared__ float wl[144];
    __shared__ float tl[128][13];
    __shared__ float tm[12][132], te[12][132];
    __shared__ __align__(16) float pbuf[8][12][128];   // 48 KB; aliases `red`
    float* red = &pbuf[0][0][0];                   // 10*512 floats, pre-canvas only
    hl[t] = h_dec[(size_t)b * HID + t];
    __syncthreads();
    // ---- 10 attn dots (5 write + 5 read)
#pragma unroll
    for (int j = 0; j < 5; ++j) {
        red[j * 512 + t] = hl[t] * Wwa[j * HID + t];
        red[(j + 5) * 512 + t] = hl[t] * Wra[j * HID + t];
    }
    __syncthreads();
    for (int o = 256; o > 0; o >>= 1) {
        if (t < o) {
#pragma unroll
            for (int j = 0; j < 10; ++j) red[j * 512 + t] += red[j * 512 + t + o];
        }
        __syncthreads();
    }
    if (t < 10) par[t] = red[t * 512] + ((t < 5) ? bwa[t] : bra[t - 5]);
    __syncthreads();
    const float gxw = 129.f * (par[0] + 1.f) * 0.5f;
    const float gyw = 129.f * (par[1] + 1.f) * 0.5f;
    const float varw = expf(par[2]);
    const float strdw = 127.f * expf(par[3]) / 11.f;
    const float riv = 1.f / expf(par[4]);
    const float gxr = 129.f * (par[5] + 1.f) * 0.5f;
    const float gyr = 129.f * (par[6] + 1.f) * 0.5f;
    const float varr = expf(par[7]);
    const float strdr = 127.f * expf(par[8]) / 11.f;
    const float ivr = expf(par[9]);
    // ---- writer patch: wave wv computes outs [18wv, 18wv+18), K=512
    {
        const int wv = t >> 6, l = t & 63;
#pragma unroll
        for (int oi = 0; oi < 18; ++oi) {
            int o = wv * 18 + oi;
            float p = 0.f;
#pragma unroll
            for (int j = 0; j < 8; ++j) p += hl[l + 64 * j] * Wwr[(size_t)o * 512 + l + 64 * j];
#pragma unroll
            for (int m = 32; m; m >>= 1) p += __shfl_xor(p, m, 64);
            if (l == 0) wl[o] = p + bwr[o];
        }
    }
    // ---- 4 filter banks (6144 entries, 12/thread)
#pragma unroll
    for (int rep = 0; rep < 12; ++rep) {
        int e = t + rep * 512;
        int mat = e / 1536;
        int idx = e - mat * 1536;
        int rr = idx >> 7, cc = idx & 127;
        float g0 = (mat == 0) ? gxw : (mat == 1) ? gyw : (mat == 2) ? gxr : gyr;
        float sd = (mat < 2) ? strdw : strdr;
        float vv = (mat < 2) ? varw : varr;
        float d = (float)cc - (g0 + ((float)rr + 0.5f - 6.f) * sd);
        float v = expf(-(d * d) / (2.f * vv));
        float* base = (mat == 0) ? &fxw[0][0] : (mat == 1) ? &fyw[0][0]
                     : (mat == 2) ? &fxr[0][0] : &fyr[0][0];
        base[rr * 132 + cc] = v;
    }
    __syncthreads();
    if (t < 48) {
        int mat = t / 12, rr = t - mat * 12;
        const float* base = (mat == 0) ? &fxw[0][0] : (mat == 1) ? &fyw[0][0]
                           : (mat == 2) ? &fxr[0][0] : &fyr[0][0];
        float s = 0.f;
        for (int k = 0; k < 128; ++k) s += base[rr * 132 + k];
        dn[t] = fmaxf(s, 1e-8f);
    }
    __syncthreads();
#pragma unroll
    for (int rep = 0; rep < 12; ++rep) {
        int e = t + rep * 512;
        int mat = e / 1536;
        int idx = e - mat * 1536;
        int rr = idx >> 7, cc = idx & 127;
        float* base = (mat == 0) ? &fxw[0][0] : (mat == 1) ? &fyw[0][0]
                     : (mat == 2) ? &fxr[0][0] : &fyr[0][0];
        base[rr * 132 + cc] /= dn[mat * 12 + rr];
    }
    __syncthreads();
    // ---- tl[h][j] = sum_i Fyw[i][h] * w[i][j]
    if (t < 128) {
        float tj[12] = {};
#pragma unroll
        for (int i = 0; i < 12; ++i) {
            float f = fyw[i][t];
#pragma unroll
            for (int j = 0; j < 12; ++j) tj[j] += f * wl[i * 12 + j];
        }
#pragma unroll
        for (int j = 0; j < 12; ++j) tl[t][j] = tj[j];
    }
    __syncthreads();
    // ---- canvas RMW + glimpse accumulate (group g rows [16g,16g+16), lane l cols {2l,2l+1})
    const int g = t >> 6, l = t & 63, c2 = l * 2;
    float2 am[12] = {}, ae[12] = {};
    const float* xb = x + (size_t)b * IMG;
    float* cb = canvas + (size_t)b * IMG;
    for (int hh = g * 16; hh < g * 16 + 16; ++hh) {
        float sx = 0.f, sy = 0.f;
#pragma unroll
        for (int j = 0; j < 12; ++j) {
            float tv = tl[hh][j];
            sx += tv * fxw[j][c2];
            sy += tv * fxw[j][c2 + 1];
        }
        float2 cv = *(float2*)(cb + hh * 128 + c2);
        cv.x += sx * riv;
        cv.y += sy * riv;
        *(float2*)(cb + hh * 128 + c2) = cv;
        float2 xv = *(const float2*)(xb + hh * 128 + c2);
        float2 xe;
        xe.x = xv.x - 1.f / (1.f + expf(-cv.x));
        xe.y = xv.y - 1.f / (1.f + expf(-cv.y));
#pragma unroll
        for (int i = 0; i < 12; ++i) {
            float f = fyr[i][hh];
            am[i].x += f * xv.x;
            am[i].y += f * xv.y;
            ae[i].x += f * xe.x;
            ae[i].y += f * xe.y;
        }
    }
    __syncthreads();   // red region dead; pbuf reuse safe
#pragma unroll
    for (int i = 0; i < 12; ++i) *(float2*)(&pbuf[g][i][c2]) = am[i];
    __syncthreads();
    for (int it = t; it < 1536; it += 512) {
        int ii = it >> 7, cc = it & 127;
        float s = 0.f;
#pragma unroll
        for (int k = 0; k < 8; ++k) s += pbuf[k][ii][cc];
        tm[ii][cc] = s;
    }
    __syncthreads();
#pragma unroll
    for (int i = 0; i < 12; ++i) *(float2*)(&pbuf[g][i][c2]) = ae[i];
    __syncthreads();
    for (int it = t; it < 1536; it += 512) {
        int ii = it >> 7, cc = it & 127;
        float s = 0.f;
#pragma unroll
        for (int k = 0; k < 8; ++k) s += pbuf[k][ii][cc];
        te[ii][cc] = s;
    }
    __syncthreads();
    // ---- FxT products (read filters) -> A_enc split
    unsigned short hi, lo;
    unsigned short* rb = A_enc + (size_t)b * 2 * SEC_E;
    if (t < 288) {
        int ch = (t >= 144) ? 1 : 0;
        int rem = t - ch * 144;
        int ii = rem / 12, jj = rem - ii * 12;
        const float* src = ch ? te[ii] : tm[ii];
        float s = 0.f;
        for (int w2 = 0; w2 < 128; ++w2) s += src[w2] * fxr[jj][w2];
        bsplit(ivr * s, hi, lo);
        rb[t] = hi;
        rb[SEC_E + t] = lo;
    }
    bsplit(hl[t], hi, lo);
    rb[288 + t] = hi;
    rb[SEC_E + 288 + t] = lo;
    if (t < 32) {
        rb[1312 + t] = 0;
        rb[SEC_E + 1312 + t] = 0;
    }
}

// ---------------------------------------------------------------- final write + sigmoid
__global__ __launch_bounds__(512, 4) void write_final_fused(float* __restrict__ canvas,
                                                            const float* __restrict__ h_dec,
                                                            const float* __restrict__ Wwa,
                                                            const float* __restrict__ bwa,
                                                            const float* __restrict__ Wwr,
                                                            const float* __restrict__ bwr) {
    const int b = blockIdx.x, t = threadIdx.x;
    __shared__ float hl[512];
    __shared__ float par[5];
    __shared__ float red[5][512];
    __shared__ float fx[12][132], fyl[12][132];
    __shared__ float dn[24];
    __shared__ float wl[144];
    __shared__ float tl[128][13];
    hl[t] = h_dec[(size_t)b * HID + t];
    __syncthreads();
#pragma unroll
    for (int j = 0; j < 5; ++j) red[j][t] = hl[t] * Wwa[j * HID + t];
    __syncthreads();
    for (int o = 256; o > 0; o >>= 1) {
        if (t < o) {
#pragma unroll
            for (int j = 0; j < 5; ++j) red[j][t] += red[j][t + o];
        }
        __syncthreads();
    }
    if (t < 5) par[t] = red[t][0] + bwa[t];
    __syncthreads();
    const float gx = 129.f * (par[0] + 1.f) * 0.5f;
    const float gy = 129.f * (par[1] + 1.f) * 0.5f;
    const float var = expf(par[2]);
    const float strd = 127.f * expf(par[3]) / 11.f;
    const float riv = 1.f / expf(par[4]);
    {
        const int wv = t >> 6, l = t & 63;
#pragma unroll
        for (int oi = 0; oi < 18; ++oi) {
            int o = wv * 18 + oi;
            float p = 0.f;
#pragma unroll
            for (int j = 0; j < 8; ++j) p += hl[l + 64 * j] * Wwr[(size_t)o * 512 + l + 64 * j];
#pragma unroll
            for (int m = 32; m; m >>= 1) p += __shfl_xor(p, m, 64);
            if (l == 0) wl[o] = p + bwr[o];
        }
    }
#pragma unroll
    for (int rep = 0; rep < 6; ++rep) {
        int e = t + rep * 512;
        int mat = e / 1536;
        int rr = (e - mat * 1536) >> 7;
        int cc = e & 127;
        float ctr = (mat ? gy : gx) + ((float)rr + 0.5f - 6.f) * strd;
        float d = (float)cc - ctr;
        float v = expf(-(d * d) / (2.f * var));
        float (*dst)[132] = mat ? fyl : fx;
        dst[rr][cc] = v;
    }
    __syncthreads();
    if (t < 24) {
        const float (*src)[132] = (t < 12) ? fx : fyl;
        int rr = (t < 12) ? t : t - 12;
        float s = 0.f;
        for (int k = 0; k < 128; ++k) s += src[rr][k];
        dn[t] = fmaxf(s, 1e-8f);
    }
    __syncthreads();
#pragma unroll
    for (int rep = 0; rep < 6; ++rep) {
        int e = t + rep * 512;
        int mat = e / 1536;
        int rr = (e - mat * 1536) >> 7;
        int cc = e & 127;
        float (*dst)[132] = mat ? fyl : fx;
        dst[rr][cc] /= dn[mat * 12 + rr];
    }
    __syncthreads();
    if (t < 128) {
        float tj[12] = {};
#pragma unroll
        for (int i = 0; i < 12; ++i) {
            float f = fyl[i][t];
#pragma unroll
            for (int j = 0; j < 12; ++j) tj[j] += f * wl[i * 12 + j];
        }
#pragma unroll
        for (int j = 0; j < 12; ++j) tl[t][j] = tj[j];
    }
    __syncthreads();
    const int g = t >> 6, l = t & 63, c2 = l * 2;
    float* cb = canvas + (size_t)b * IMG;
    for (int hh = g * 16; hh < g * 16 + 16; ++hh) {
        float sx = 0.f, sy = 0.f;
#pragma unroll
        for (int j = 0; j < 12; ++j) {
            float tv = tl[hh][j];
            sx += tv * fx[j][c2];
            sy += tv * fx[j][c2 + 1];
        }
        float2 cv = *(float2*)(cb + hh * 128 + c2);
        cv.x = 1.f / (1.f + expf(-(cv.x + sx * riv)));
        cv.y = 1.f / (1.f + expf(-(cv.y + sy * riv)));
        *(float2*)(cb + hh * 128 + c2) = cv;
    }
}

// ---------------------------------------------------------------- enc LSTM + samp GEMM + z (4 b/block)
__global__ __launch_bounds__(512, 2) void lstm_enc_samp_z(const float* __restrict__ g0,
                                                          const float* __restrict__ g1,
                                                          const float* __restrict__ bih,
                                                          const float* __restrict__ bhh,
                                                          float* __restrict__ h,
                                                          float* __restrict__ c,
                                                          unsigned short* __restrict__ A_enc,
                                                          const float* __restrict__ WsT,
                                                          const float* __restrict__ bs,
                                                          const float* __restrict__ eps_t,
                                                          unsigned short* __restrict__ A_dec,
                                                          float* __restrict__ mu_out,
                                                          float* __restrict__ lv_out, int t) {
    const int bb = blockIdx.x * 4;
    const int tid = threadIdx.x;
    __shared__ float hl[4][512];
    __shared__ float sred[2][4][256];
    __shared__ float sfin[4][256];
    unsigned short hi, lo;
#pragma unroll
    for (int q = 0; q < 4; ++q) {
        const int b = bb + q, u = tid;
        size_t base = (size_t)b * GATES;
        float gi = g0[base + u] + g1[base + u] + bih[u] + bhh[u];
        float gf = g0[base + 512 + u] + g1[base + 512 + u] + bih[512 + u] + bhh[512 + u];
        float gg = g0[base + 1024 + u] + g1[base + 1024 + u] + bih[1024 + u] + bhh[1024 + u];
        float go = g0[base + 1536 + u] + g1[base + 1536 + u] + bih[1536 + u] + bhh[1536 + u];
        float si = 1.f / (1.f + expf(-gi));
        float sf = 1.f / (1.f + expf(-gf));
        float so = 1.f / (1.f + expf(-go));
        size_t cidx = (size_t)b * HID + u;
        float cn = sf * c[cidx] + si * tanhf(gg);
        c[cidx] = cn;
        float hn = so * tanhf(cn);
        h[cidx] = hn;
        hl[q][u] = hn;
        bsplit(hn, hi, lo);
        size_t sb = (size_t)b * 2 * SEC_E;
        A_enc[sb + 800 + u] = hi;
        A_enc[sb + SEC_E + 800 + u] = lo;
    }
    __syncthreads();
    // samp: output o = tid&255, K-half = tid>>8; 4 batches share weight loads
    {
        const int o = tid & 255, half = tid >> 8;
        float p0 = 0.f, p1 = 0.f, p2 = 0.f, p3 = 0.f;
        for (int k = half * 256; k < half * 256 + 256; ++k) {
            float w = WsT[k * 256 + o];
            p0 += hl[0][k] * w;
            p1 += hl[1][k] * w;
            p2 += hl[2][k] * w;
            p3 += hl[3][k] * w;
        }
        sred[half][0][o] = p0;
        sred[half][1][o] = p1;
        sred[half][2][o] = p2;
        sred[half][3][o] = p3;
    }
    __syncthreads();
#pragma unroll
    for (int r = 0; r < 2; ++r) {
        int idx = tid + r * 512;        // 0..1023 over (q, o)
        int q = idx >> 8, o = idx & 255;
        sfin[q][o] = sred[0][q][o] + sred[1][q][o] + bs[o];
    }
    __syncthreads();
    // z for (q, l): 4*128 = 512 threads
    {
        const int q = tid >> 7, l = tid & 127;
        const int b = bb + q;
        float mu = sfin[q][l], lv = sfin[q][l + 128];
        float zv = mu + expf(0.5f * lv) * eps_t[(size_t)b * LAT + l];
        bsplit(zv, hi, lo);
        size_t bd = (size_t)b * 2 * SEC_D;
        A_dec[bd + l] = hi;
        A_dec[bd + SEC_D + l] = lo;
        size_t o = (size_t)b * (TSTEPS * LAT) + t * LAT + l;
        mu_out[o] = mu;
        lv_out[o] = lv;
    }
}

// ---------------------------------------------------------------- dec LSTM pointwise
__global__ __launch_bounds__(256) void lstm_pw(const float* __restrict__ g0,
                                               const float* __restrict__ g1,
                                               const float* __restrict__ bih,
                                               const float* __restrict__ bhh,
                                               float* __restrict__ h, float* __restrict__ c,
                                               unsigned short* __restrict__ split_out,
                                               int soff, int SEC2) {
    int idx = blockIdx.x * 256 + threadIdx.x;  // B*HID
    int b = idx >> 9, u = idx & 511;
    size_t base = (size_t)b * GATES;
    float gi = g0[base + u] + g1[base + u] + bih[u] + bhh[u];
    float gf = g0[base + 512 + u] + g1[base + 512 + u] + bih[512 + u] + bhh[512 + u];
    float gg = g0[base + 1024 + u] + g1[base + 1024 + u] + bih[1024 + u] + bhh[1024 + u];
    float go = g0[base + 1536 + u] + g1[base + 1536 + u] + bih[1536 + u] + bhh[1536 + u];
    float si = 1.f / (1.f + expf(-gi));
    float sf = 1.f / (1.f + expf(-gf));
    float so = 1.f / (1.f + expf(-go));
    float cn = sf * c[idx] + si * tanhf(gg);
    c[idx] = cn;
    float hn = so * tanhf(cn);
    h[idx] = hn;
    unsigned short hi, lo;
    bsplit(hn, hi, lo);
    size_t sb = (size_t)b * 2 * SEC2;
    split_out[sb + soff + u] = hi;
    split_out[sb + SEC2 + soff + u] = lo;
}

// ================================================================ host
extern "C" void kernel_launch(void* const* d_in, const int* in_sizes, int n_in,
                              void* d_out, int out_size, void* d_ws, size_t ws_size,
                              hipStream_t stream) {
    const float* x = (const float*)d_in[0];
    const float* eps = (const float*)d_in[1];
    const float* canvas_init = (const float*)d_in[3];
    const float* h_dec_init = (const float*)d_in[4];
    const float* h_enc_init = (const float*)d_in[5];
    const float* W_ih_enc = (const float*)d_in[6];
    const float* b_ih_enc = (const float*)d_in[7];
    const float* W_hh_enc = (const float*)d_in[8];
    const float* b_hh_enc = (const float*)d_in[9];
    const float* W_ih_dec = (const float*)d_in[10];
    const float* b_ih_dec = (const float*)d_in[11];
    const float* W_hh_dec = (const float*)d_in[12];
    const float* b_hh_dec = (const float*)d_in[13];
    const float* W_samp = (const float*)d_in[14];
    const float* b_samp = (const float*)d_in[15];
    const float* W_rattn = (const float*)d_in[16];
    const float* b_rattn = (const float*)d_in[17];
    const float* W_wattn = (const float*)d_in[18];
    const float* b_wattn = (const float*)d_in[19];
    const float* W_writer = (const float*)d_in[20];
    const float* b_writer = (const float*)d_in[21];

    float* out = (float*)d_out;
    float* canvas = out;
    float* out_mu = out + (size_t)BATCH * IMG;
    float* out_lv = out_mu + (size_t)BATCH * TSTEPS * LAT;

    float* ws = (float*)d_ws;
    size_t off = 0;
    auto alloc = [&](size_t n) { float* p = ws + off; off += n; return p; };
    float* h_enc = alloc((size_t)BATCH * HID);
    float* c_enc = alloc((size_t)BATCH * HID);
    float* h_dec = alloc((size_t)BATCH * HID);
    float* c_dec = alloc((size_t)BATCH * HID);
    float* gates = alloc((size_t)2 * BATCH * GATES);
    float* WsT = alloc((size_t)HID * 256);
    unsigned short* A_enc = (unsigned short*)alloc((size_t)BATCH * SEC_E);
    unsigned short* A_dec = (unsigned short*)alloc((size_t)BATCH * SEC_D);
    unsigned short* Ws_enc = (unsigned short*)alloc((size_t)GATES * SEC_E);
    unsigned short* Ws_dec = (unsigned short*)alloc((size_t)GATES * SEC_D);

    init_canvas<<<BATCH * IMG / 256, 256, 0, stream>>>(canvas, canvas_init);
    init_state<<<BATCH * HID / 256, 256, 0, stream>>>(h_enc, c_enc, h_dec, c_dec,
                                                      h_enc_init, h_dec_init, A_enc, A_dec);
    prep_wsplit<<<dim3((SEC_E + 255) / 256, GATES), 256, 0, stream>>>(W_ih_enc, ENC_IN, W_hh_enc, HID, Ws_enc, SEC_E);
    prep_wsplit<<<dim3((SEC_D + 255) / 256, GATES), 256, 0, stream>>>(W_ih_dec, LAT, W_hh_dec, HID, Ws_dec, SEC_D);
    prep_wsampT<<<HID * 256 / 256, 256, 0, stream>>>(W_samp, WsT);

    const int ktE = 3 * SEC_E / 64;   // 63
    const int ktD = 3 * SEC_D / 64;   // 30

    // read for step 0
    read_glimpse_fused<<<BATCH, 512, 0, stream>>>(x, canvas, h_dec, W_rattn, b_rattn, A_enc);

    for (int t = 0; t < TSTEPS; ++t) {
        gemm_bf16x3<<<dim3(BATCH / 64, GATES / 64, 2), 256, 0, stream>>>(
            A_enc, Ws_enc, gates, SEC_E, 0, 32, 32, ktE);
        lstm_enc_samp_z<<<BATCH / 4, 512, 0, stream>>>(
            gates, gates + (size_t)BATCH * GATES, b_ih_enc, b_hh_enc, h_enc, c_enc, A_enc,
            WsT, b_samp, eps + (size_t)t * BATCH * LAT, A_dec, out_mu, out_lv, t);
        gemm_bf16x3<<<dim3(BATCH / 64, GATES / 64, 2), 256, 0, stream>>>(
            A_dec, Ws_dec, gates, SEC_D, 0, 15, 15, ktD);
        lstm_pw<<<BATCH * HID / 256, 256, 0, stream>>>(gates, gates + (size_t)BATCH * GATES,
                                                       b_ih_dec, b_hh_dec, h_dec, c_dec,
                                                       A_dec, 128, SEC_D);
        if (t < TSTEPS - 1) {
            rw_canvas_fused<<<BATCH, 512, 0, stream>>>(canvas, x, h_dec,
                                                       W_wattn, b_wattn, W_writer, b_writer,
                                                       W_rattn, b_rattn, A_enc);
        } else {
            write_final_fused<<<BATCH, 512, 0, stream>>>(canvas, h_dec,
                                                         W_wattn, b_wattn, W_writer, b_writer);
        }
    }
}

// Round 8
// 1955.222 us; speedup vs baseline: 1.4511x; 1.4511x over previous
//
#include <hip/hip_runtime.h>
#include <hip/hip_bf16.h>
#include <math.h>

// DRAW: B=512, C=1, H=W=128, RS=WS=12, L=128, HID=512, T=16
#define BATCH 512
#define HID 512
#define LAT 128
#define TSTEPS 16
#define IMG 16384      // 128*128
#define ENC_IN 800     // 2*12*12 + 512
#define GATES 2048     // 4*HID

// bf16x3 split-GEMM geometry. A and W stored [hi | lo]; virtual K = 3*SEC:
// hi*hi, hi*lo, lo*hi (lo*lo dropped, ~2^-16 relative).
// A_enc row: [glimpse 288 | h_dec 512 | h_enc 512 | pad 32] = 1344
// A_dec row: [z 128 | h_dec 512] = 640
#define SEC_E 1344
#define SEC_D 640

typedef __attribute__((ext_vector_type(8))) short short8;
typedef __attribute__((ext_vector_type(4))) float f32x4;

// ---------------------------------------------------------------- helpers
__device__ __forceinline__ void gload16(const void* g, void* l) {
    __builtin_amdgcn_global_load_lds((const __attribute__((address_space(1))) unsigned int*)g,
                                     (__attribute__((address_space(3))) unsigned int*)l, 16, 0, 0);
}

__device__ __forceinline__ void bsplit(float v, unsigned short& hi, unsigned short& lo) {
    unsigned u = __float_as_uint(v);
    unsigned uh = (u + (0x7FFFu + ((u >> 16) & 1u))) & 0xFFFF0000u;   // RNE bf16
    hi = (unsigned short)(uh >> 16);
    float r = v - __uint_as_float(uh);                                 // exact residual
    unsigned ur = __float_as_uint(r);
    unsigned ul = (ur + (0x7FFFu + ((ur >> 16) & 1u))) & 0xFFFF0000u;
    lo = (unsigned short)(ul >> 16);
}

// ---------------------------------------------------------------- init
__global__ __launch_bounds__(256) void init_canvas(float* __restrict__ canvas,
                                                   const float* __restrict__ ci) {
    int idx = blockIdx.x * 256 + threadIdx.x;
    canvas[idx] = ci[idx & (IMG - 1)];
}

__global__ __launch_bounds__(256) void init_state(float* __restrict__ ce,
                                                  float* __restrict__ hd, float* __restrict__ cd,
                                                  const float* __restrict__ hei,
                                                  const float* __restrict__ hdi,
                                                  unsigned short* __restrict__ A_enc,
                                                  unsigned short* __restrict__ A_dec) {
    int idx = blockIdx.x * 256 + threadIdx.x;   // B*HID
    int b = idx >> 9, u = idx & 511;
    float ve = hei[u], vd = hdi[u];
    hd[idx] = vd;
    ce[idx] = 0.f;
    cd[idx] = 0.f;
    unsigned short hi, lo;
    bsplit(ve, hi, lo);
    size_t be = (size_t)b * 2 * SEC_E;
    A_enc[be + 800 + u] = hi;
    A_enc[be + SEC_E + 800 + u] = lo;
    bsplit(vd, hi, lo);
    size_t bd = (size_t)b * 2 * SEC_D;
    A_dec[bd + 128 + u] = hi;
    A_dec[bd + SEC_D + 128 + u] = lo;
}

// ---------------------------------------------------------------- weight preps (once/launch)
__global__ __launch_bounds__(256) void prep_wsplit(const float* __restrict__ W1, int K1,
                                                   const float* __restrict__ W2, int K2,
                                                   unsigned short* __restrict__ out, int SEC) {
    int kk = blockIdx.x * 256 + threadIdx.x;
    int n = blockIdx.y;
    if (kk >= SEC) return;
    float v = 0.f;
    if (kk < K1) v = W1[(size_t)n * K1 + kk];
    else if (kk < K1 + K2) v = W2[(size_t)n * K2 + (kk - K1)];
    unsigned short hi, lo;
    bsplit(v, hi, lo);
    size_t base = (size_t)n * 2 * SEC;
    out[base + kk] = hi;
    out[base + SEC + kk] = lo;
}

// W_samp (256x512) -> WsT (512x256)
__global__ __launch_bounds__(256) void prep_wsampT(const float* __restrict__ W,
                                                   float* __restrict__ WT) {
    int i = blockIdx.x * 256 + threadIdx.x;   // 131072
    int o = i >> 9, k = i & 511;
    WT[k * 256 + o] = W[o * 512 + k];
}

// ---------------------------------------------------------------- bf16x3 MFMA GEMM
__global__ __launch_bounds__(256) void gemm_bf16x3(const unsigned short* __restrict__ Au,
                                                   const unsigned short* __restrict__ Wu,
                                                   float* __restrict__ C, int SEC,
                                                   int ktb0, int kte0, int ktb1, int kte1) {
    __shared__ __align__(16) char lds[2][16384];   // per buf: A [0,8192), B [8192,16384)
    const __bf16* A = (const __bf16*)Au;
    const __bf16* Wt = (const __bf16*)Wu;
    const int ld = 2 * SEC;
    const int tid = threadIdx.x;
    const int z = blockIdx.z;
    const int bm = blockIdx.x * 64;
    const int bn = blockIdx.y * 64;
    const int ktb = z ? ktb1 : ktb0;
    const int kte = z ? kte1 : kte0;

    const int row0 = tid >> 3, c0 = tid & 7;
    const size_t ga0 = (size_t)(bm + row0) * ld + (size_t)((c0 ^ (row0 & 7)) * 8);
    const size_t ga1 = ga0 + (size_t)32 * ld;
    const size_t gb0 = (size_t)(bn + row0) * ld + (size_t)((c0 ^ (row0 & 7)) * 8);
    const size_t gb1 = gb0 + (size_t)32 * ld;
    const int lA0 = tid * 16, lA1 = (tid + 256) * 16;
    const int lB0 = 8192 + tid * 16, lB1 = 8192 + (tid + 256) * 16;

    const int lane = tid & 63, wv = tid >> 6;
    const int rA = wv * 16 + (lane & 15);
    const int chnk = (lane >> 4) ^ (lane & 7);
    const int byteA = rA * 128 + chnk * 16;
    const int byteB = 8192 + (lane & 15) * 128 + chnk * 16;

    f32x4 acc[4];
#pragma unroll
    for (int j = 0; j < 4; ++j) acc[j] = (f32x4){0.f, 0.f, 0.f, 0.f};

    auto STAGE = [&](int buf, int kt) {
        const int kw = kt * 64;
        const int ka = (kw >= SEC) ? (kw - SEC) : kw;            // A: hi,hi,lo
        const int kb = (kw >= 2 * SEC) ? (kw - 2 * SEC) : kw;    // W: hi,lo,hi
        const __bf16* a = A + ka;
        const __bf16* w = Wt + kb;
        char* l = &lds[buf][0];
        gload16(a + ga0, l + lA0);
        gload16(a + ga1, l + lA1);
        gload16(w + gb0, l + lB0);
        gload16(w + gb1, l + lB1);
    };

    STAGE(0, ktb);
    asm volatile("s_waitcnt vmcnt(0)" ::: "memory");
    __syncthreads();
    int buf = 0;
    for (int kt = ktb; kt < kte; ++kt) {
        if (kt + 1 < kte) STAGE(buf ^ 1, kt + 1);
        const char* base = &lds[buf][0];
        short8 a0 = *(const short8*)(base + byteA);
        short8 a1 = *(const short8*)(base + (byteA ^ 64));
#pragma unroll
        for (int j = 0; j < 4; ++j) {
            short8 b0 = *(const short8*)(base + (byteB + j * 2048));
            short8 b1 = *(const short8*)(base + ((byteB + j * 2048) ^ 64));
            acc[j] = __builtin_amdgcn_mfma_f32_16x16x32_bf16(a0, b0, acc[j], 0, 0, 0);
            acc[j] = __builtin_amdgcn_mfma_f32_16x16x32_bf16(a1, b1, acc[j], 0, 0, 0);
        }
        asm volatile("s_waitcnt vmcnt(0)" ::: "memory");
        __syncthreads();
        buf ^= 1;
    }
    float* Cz = C + (size_t)z * BATCH * GATES;
    const int crow = bm + wv * 16 + (lane >> 4) * 4;
    const int ccol = bn + (lane & 15);
#pragma unroll
    for (int j = 0; j < 4; ++j)
#pragma unroll
        for (int r = 0; r < 4; ++r)
            Cz[(size_t)(crow + r) * GATES + ccol + j * 16] = acc[j][r];
}

// ---------------------------------------------------------------- fused read (512 thr)
// attn params + filter bank + glimpse; writes split glimpse|h_dec into A_enc.
__global__ __launch_bounds__(512, 4) void read_glimpse_fused(const float* __restrict__ x,
                                                             const float* __restrict__ canvas,
                                                             const float* __restrict__ h_dec,
                                                             const float* __restrict__ Wa,
                                                             const float* __restrict__ ba,
                                                             unsigned short* __restrict__ A_enc) {
    const int b = blockIdx.x, t = threadIdx.x;
    __shared__ float par[5];
    __shared__ float fx[12][132], fy[12][132];
    __shared__ float dn[24];
    __shared__ float tm[12][132], te[12][132];
    __shared__ __align__(16) float pbuf[8][12][128];   // 48 KB; aliases `red`
    float* red = &pbuf[0][0][0];
    const float* hb = h_dec + (size_t)b * HID;
#pragma unroll
    for (int j = 0; j < 5; ++j) red[j * 512 + t] = hb[t] * Wa[j * HID + t];
    __syncthreads();
    for (int o = 256; o > 0; o >>= 1) {
        if (t < o) {
#pragma unroll
            for (int j = 0; j < 5; ++j) red[j * 512 + t] += red[j * 512 + t + o];
        }
        __syncthreads();
    }
    if (t < 5) par[t] = red[t * 512] + ba[t];
    __syncthreads();
    const float gx = 129.f * (par[0] + 1.f) * 0.5f;
    const float gy = 129.f * (par[1] + 1.f) * 0.5f;
    const float var = expf(par[2]);
    const float strd = 127.f * expf(par[3]) / 11.f;
    const float iv = expf(par[4]);
#pragma unroll
    for (int rep = 0; rep < 6; ++rep) {
        int e = t + rep * 512;
        int mat = e / 1536;
        int rr = (e - mat * 1536) >> 7;
        int cc = e & 127;
        float ctr = (mat ? gy : gx) + ((float)rr + 0.5f - 6.f) * strd;
        float d = (float)cc - ctr;
        float v = expf(-(d * d) / (2.f * var));
        float (*dst)[132] = mat ? fy : fx;
        dst[rr][cc] = v;
    }
    __syncthreads();
    if (t < 24) {
        const float (*src)[132] = (t < 12) ? fx : fy;
        int rr = (t < 12) ? t : t - 12;
        float s = 0.f;
        for (int k = 0; k < 128; ++k) s += src[rr][k];
        dn[t] = fmaxf(s, 1e-8f);
    }
    __syncthreads();
#pragma unroll
    for (int rep = 0; rep < 6; ++rep) {
        int e = t + rep * 512;
        int mat = e / 1536;
        int rr = (e - mat * 1536) >> 7;
        int cc = e & 127;
        float (*dst)[132] = mat ? fy : fx;
        dst[rr][cc] /= dn[mat * 12 + rr];
    }
    __syncthreads();
    const int g = t >> 6, l = t & 63, c2 = l * 2;
    float2 am[12] = {}, ae[12] = {};
    const float* xb = x + (size_t)b * IMG;
    const float* cb = canvas + (size_t)b * IMG;
    for (int hh = g * 16; hh < g * 16 + 16; ++hh) {
        float2 xv = *(const float2*)(xb + hh * 128 + c2);
        float2 cv = *(const float2*)(cb + hh * 128 + c2);
        float2 xe;
        xe.x = xv.x - 1.f / (1.f + expf(-cv.x));
        xe.y = xv.y - 1.f / (1.f + expf(-cv.y));
#pragma unroll
        for (int i = 0; i < 12; ++i) {
            float f = fy[i][hh];
            am[i].x += f * xv.x;
            am[i].y += f * xv.y;
            ae[i].x += f * xe.x;
            ae[i].y += f * xe.y;
        }
    }
#pragma unroll
    for (int i = 0; i < 12; ++i) *(float2*)(&pbuf[g][i][c2]) = am[i];
    __syncthreads();
    for (int it = t; it < 1536; it += 512) {
        int ii = it >> 7, cc = it & 127;
        float s = 0.f;
#pragma unroll
        for (int k = 0; k < 8; ++k) s += pbuf[k][ii][cc];
        tm[ii][cc] = s;
    }
    __syncthreads();
#pragma unroll
    for (int i = 0; i < 12; ++i) *(float2*)(&pbuf[g][i][c2]) = ae[i];
    __syncthreads();
    for (int it = t; it < 1536; it += 512) {
        int ii = it >> 7, cc = it & 127;
        float s = 0.f;
#pragma unroll
        for (int k = 0; k < 8; ++k) s += pbuf[k][ii][cc];
        te[ii][cc] = s;
    }
    __syncthreads();
    unsigned short hi, lo;
    unsigned short* rb = A_enc + (size_t)b * 2 * SEC_E;
    if (t < 288) {
        int ch = (t >= 144) ? 1 : 0;
        int rem = t - ch * 144;
        int ii = rem / 12, jj = rem - ii * 12;
        const float* src = ch ? te[ii] : tm[ii];
        float s = 0.f;
        for (int w2 = 0; w2 < 128; ++w2) s += src[w2] * fx[jj][w2];
        bsplit(iv * s, hi, lo);
        rb[t] = hi;
        rb[SEC_E + t] = lo;
    }
    bsplit(hb[t], hi, lo);
    rb[288 + t] = hi;
    rb[SEC_E + 288 + t] = lo;
    if (t < 32) {       // zero the K pad (ws is re-poisoned each launch)
        rb[1312 + t] = 0;
        rb[SEC_E + 1312 + t] = 0;
    }
}

// ---------------------------------------------------------------- enc LSTM + samp + z, 1 batch/block
__global__ __launch_bounds__(512, 4) void lstm_enc_samp_z(const float* __restrict__ g0,
                                                          const float* __restrict__ g1,
                                                          const float* __restrict__ bih,
                                                          const float* __restrict__ bhh,
                                                          float* __restrict__ c,
                                                          unsigned short* __restrict__ A_enc,
                                                          const float* __restrict__ WsT,
                                                          const float* __restrict__ bs,
                                                          const float* __restrict__ eps_t,
                                                          unsigned short* __restrict__ A_dec,
                                                          float* __restrict__ mu_out,
                                                          float* __restrict__ lv_out, int t) {
    const int b = blockIdx.x, tid = threadIdx.x;
    __shared__ float hl[512];
    __shared__ float sred[2][256];
    __shared__ float sfin[256];
    unsigned short hi, lo;
    // ---- LSTM cell, unit u = tid
    {
        size_t base = (size_t)b * GATES;
        float gi = g0[base + tid] + g1[base + tid] + bih[tid] + bhh[tid];
        float gf = g0[base + 512 + tid] + g1[base + 512 + tid] + bih[512 + tid] + bhh[512 + tid];
        float gg = g0[base + 1024 + tid] + g1[base + 1024 + tid] + bih[1024 + tid] + bhh[1024 + tid];
        float go = g0[base + 1536 + tid] + g1[base + 1536 + tid] + bih[1536 + tid] + bhh[1536 + tid];
        float si = 1.f / (1.f + expf(-gi));
        float sf = 1.f / (1.f + expf(-gf));
        float so = 1.f / (1.f + expf(-go));
        size_t cidx = (size_t)b * HID + tid;
        float cn = sf * c[cidx] + si * tanhf(gg);
        c[cidx] = cn;
        float hn = so * tanhf(cn);
        hl[tid] = hn;
        bsplit(hn, hi, lo);
        size_t sb = (size_t)b * 2 * SEC_E;
        A_enc[sb + 800 + tid] = hi;
        A_enc[sb + SEC_E + 800 + tid] = lo;
    }
    __syncthreads();
    // ---- samp: output o = tid&255, K-half = tid>>8 (coalesced WsT reads)
    {
        const int o = tid & 255, half = tid >> 8;
        float p = 0.f;
#pragma unroll 4
        for (int k = half * 256; k < half * 256 + 256; ++k) p += hl[k] * WsT[k * 256 + o];
        sred[half][o] = p;
    }
    __syncthreads();
    if (tid < 256) sfin[tid] = sred[0][tid] + sred[1][tid] + bs[tid];
    __syncthreads();
    // ---- z (threads 0..127)
    if (tid < 128) {
        float mu = sfin[tid], lv = sfin[tid + 128];
        float zv = mu + expf(0.5f * lv) * eps_t[(size_t)b * LAT + tid];
        bsplit(zv, hi, lo);
        size_t bd = (size_t)b * 2 * SEC_D;
        A_dec[bd + tid] = hi;
        A_dec[bd + SEC_D + tid] = lo;
        size_t o = (size_t)b * (TSTEPS * LAT) + t * LAT + tid;
        mu_out[o] = mu;
        lv_out[o] = lv;
    }
}

// ---------------------------------------------------------------- dec LSTM pointwise
__global__ __launch_bounds__(256) void lstm_pw(const float* __restrict__ g0,
                                               const float* __restrict__ g1,
                                               const float* __restrict__ bih,
                                               const float* __restrict__ bhh,
                                               float* __restrict__ h, float* __restrict__ c,
                                               unsigned short* __restrict__ split_out,
                                               int soff, int SEC2) {
    int idx = blockIdx.x * 256 + threadIdx.x;  // B*HID
    int b = idx >> 9, u = idx & 511;
    size_t base = (size_t)b * GATES;
    float gi = g0[base + u] + g1[base + u] + bih[u] + bhh[u];
    float gf = g0[base + 512 + u] + g1[base + 512 + u] + bih[512 + u] + bhh[512 + u];
    float gg = g0[base + 1024 + u] + g1[base + 1024 + u] + bih[1024 + u] + bhh[1024 + u];
    float go = g0[base + 1536 + u] + g1[base + 1536 + u] + bih[1536 + u] + bhh[1536 + u];
    float si = 1.f / (1.f + expf(-gi));
    float sf = 1.f / (1.f + expf(-gf));
    float so = 1.f / (1.f + expf(-go));
    float cn = sf * c[idx] + si * tanhf(gg);
    c[idx] = cn;
    float hn = so * tanhf(cn);
    h[idx] = hn;
    unsigned short hi, lo;
    bsplit(hn, hi, lo);
    size_t sb = (size_t)b * 2 * SEC2;
    split_out[sb + soff + u] = hi;
    split_out[sb + SEC2 + soff + u] = lo;
}

// ---------------------------------------------------------------- fused write (512 thr)
// writer GEMM (in-block) + attn params + filter bank + canvas += FyT@w@Fx / inten
__global__ __launch_bounds__(512, 4) void write_canvas_fused(float* __restrict__ canvas,
                                                             const float* __restrict__ h_dec,
                                                             const float* __restrict__ Wr,
                                                             const float* __restrict__ bwr,
                                                             const float* __restrict__ Wa,
                                                             const float* __restrict__ ba) {
    const int b = blockIdx.x, t = threadIdx.x;
    __shared__ float par[5];
    __shared__ float hl[512];
    __shared__ float red[5][512];
    __shared__ float fx[12][132], fyl[12][132];
    __shared__ float dn[24];
    __shared__ float wl[144];
    __shared__ float tl[128][13];
    hl[t] = h_dec[(size_t)b * HID + t];
    __syncthreads();
#pragma unroll
    for (int j = 0; j < 5; ++j) red[j][t] = hl[t] * Wa[j * HID + t];
    __syncthreads();
    for (int o = 256; o > 0; o >>= 1) {
        if (t < o) {
#pragma unroll
            for (int j = 0; j < 5; ++j) red[j][t] += red[j][t + o];
        }
        __syncthreads();
    }
    if (t < 5) par[t] = red[t][0] + ba[t];
    __syncthreads();
    const float gx = 129.f * (par[0] + 1.f) * 0.5f;
    const float gy = 129.f * (par[1] + 1.f) * 0.5f;
    const float var = expf(par[2]);
    const float strd = 127.f * expf(par[3]) / 11.f;
    const float riv = 1.f / expf(par[4]);
#pragma unroll
    for (int rep = 0; rep < 6; ++rep) {
        int e = t + rep * 512;
        int mat = e / 1536;
        int rr = (e - mat * 1536) >> 7;
        int cc = e & 127;
        float ctr = (mat ? gy : gx) + ((float)rr + 0.5f - 6.f) * strd;
        float d = (float)cc - ctr;
        float v = expf(-(d * d) / (2.f * var));
        float (*dst)[132] = mat ? fyl : fx;
        dst[rr][cc] = v;
    }
    // writer GEMM: wave wv computes outs [18*wv, 18*wv+18), K=512
    {
        const int wv = t >> 6, l = t & 63;
#pragma unroll
        for (int oi = 0; oi < 18; ++oi) {
            int o = wv * 18 + oi;
            float p = 0.f;
#pragma unroll
            for (int j = 0; j < 8; ++j) p += hl[l + 64 * j] * Wr[(size_t)o * 512 + l + 64 * j];
#pragma unroll
            for (int m = 32; m; m >>= 1) p += __shfl_xor(p, m, 64);
            if (l == 0) wl[o] = p + bwr[o];
        }
    }
    __syncthreads();
    if (t < 24) {
        const float (*src)[132] = (t < 12) ? fx : fyl;
        int rr = (t < 12) ? t : t - 12;
        float s = 0.f;
        for (int k = 0; k < 128; ++k) s += src[rr][k];
        dn[t] = fmaxf(s, 1e-8f);
    }
    __syncthreads();
#pragma unroll
    for (int rep = 0; rep < 6; ++rep) {
        int e = t + rep * 512;
        int mat = e / 1536;
        int rr = (e - mat * 1536) >> 7;
        int cc = e & 127;
        float (*dst)[132] = mat ? fyl : fx;
        dst[rr][cc] /= dn[mat * 12 + rr];
    }
    __syncthreads();
    if (t < 128) {
        float tj[12] = {};
#pragma unroll
        for (int i = 0; i < 12; ++i) {
            float f = fyl[i][t];
#pragma unroll
            for (int j = 0; j < 12; ++j) tj[j] += f * wl[i * 12 + j];
        }
#pragma unroll
        for (int j = 0; j < 12; ++j) tl[t][j] = tj[j];
    }
    __syncthreads();
    const int g = t >> 6, l = t & 63, c2 = l * 2;
    float* cb = canvas + (size_t)b * IMG;
    for (int hh = g * 16; hh < g * 16 + 16; ++hh) {
        float sx = 0.f, sy = 0.f;
#pragma unroll
        for (int j = 0; j < 12; ++j) {
            float tv = tl[hh][j];
            sx += tv * fx[j][c2];
            sy += tv * fx[j][c2 + 1];
        }
        float2 cv = *(float2*)(cb + hh * 128 + c2);
        cv.x += sx * riv;
        cv.y += sy * riv;
        *(float2*)(cb + hh * 128 + c2) = cv;
    }
}

// ---------------------------------------------------------------- final write + sigmoid (t=15)
__global__ __launch_bounds__(512, 4) void write_final_fused(float* __restrict__ canvas,
                                                            const float* __restrict__ h_dec,
                                                            const float* __restrict__ Wwa,
                                                            const float* __restrict__ bwa,
                                                            const float* __restrict__ Wwr,
                                                            const float* __restrict__ bwr) {
    const int b = blockIdx.x, t = threadIdx.x;
    __shared__ float hl[512];
    __shared__ float par[5];
    __shared__ float red[5][512];
    __shared__ float fx[12][132], fyl[12][132];
    __shared__ float dn[24];
    __shared__ float wl[144];
    __shared__ float tl[128][13];
    hl[t] = h_dec[(size_t)b * HID + t];
    __syncthreads();
#pragma unroll
    for (int j = 0; j < 5; ++j) red[j][t] = hl[t] * Wwa[j * HID + t];
    __syncthreads();
    for (int o = 256; o > 0; o >>= 1) {
        if (t < o) {
#pragma unroll
            for (int j = 0; j < 5; ++j) red[j][t] += red[j][t + o];
        }
        __syncthreads();
    }
    if (t < 5) par[t] = red[t][0] + bwa[t];
    __syncthreads();
    const float gx = 129.f * (par[0] + 1.f) * 0.5f;
    const float gy = 129.f * (par[1] + 1.f) * 0.5f;
    const float var = expf(par[2]);
    const float strd = 127.f * expf(par[3]) / 11.f;
    const float riv = 1.f / expf(par[4]);
    {
        const int wv = t >> 6, l = t & 63;
#pragma unroll
        for (int oi = 0; oi < 18; ++oi) {
            int o = wv * 18 + oi;
            float p = 0.f;
#pragma unroll
            for (int j = 0; j < 8; ++j) p += hl[l + 64 * j] * Wwr[(size_t)o * 512 + l + 64 * j];
#pragma unroll
            for (int m = 32; m; m >>= 1) p += __shfl_xor(p, m, 64);
            if (l == 0) wl[o] = p + bwr[o];
        }
    }
#pragma unroll
    for (int rep = 0; rep < 6; ++rep) {
        int e = t + rep * 512;
        int mat = e / 1536;
        int rr = (e - mat * 1536) >> 7;
        int cc = e & 127;
        float ctr = (mat ? gy : gx) + ((float)rr + 0.5f - 6.f) * strd;
        float d = (float)cc - ctr;
        float v = expf(-(d * d) / (2.f * var));
        float (*dst)[132] = mat ? fyl : fx;
        dst[rr][cc] = v;
    }
    __syncthreads();
    if (t < 24) {
        const float (*src)[132] = (t < 12) ? fx : fyl;
        int rr = (t < 12) ? t : t - 12;
        float s = 0.f;
        for (int k = 0; k < 128; ++k) s += src[rr][k];
        dn[t] = fmaxf(s, 1e-8f);
    }
    __syncthreads();
#pragma unroll
    for (int rep = 0; rep < 6; ++rep) {
        int e = t + rep * 512;
        int mat = e / 1536;
        int rr = (e - mat * 1536) >> 7;
        int cc = e & 127;
        float (*dst)[132] = mat ? fyl : fx;
        dst[rr][cc] /= dn[mat * 12 + rr];
    }
    __syncthreads();
    if (t < 128) {
        float tj[12] = {};
#pragma unroll
        for (int i = 0; i < 12; ++i) {
            float f = fyl[i][t];
#pragma unroll
            for (int j = 0; j < 12; ++j) tj[j] += f * wl[i * 12 + j];
        }
#pragma unroll
        for (int j = 0; j < 12; ++j) tl[t][j] = tj[j];
    }
    __syncthreads();
    const int g = t >> 6, l = t & 63, c2 = l * 2;
    float* cb = canvas + (size_t)b * IMG;
    for (int hh = g * 16; hh < g * 16 + 16; ++hh) {
        float sx = 0.f, sy = 0.f;
#pragma unroll
        for (int j = 0; j < 12; ++j) {
            float tv = tl[hh][j];
            sx += tv * fx[j][c2];
            sy += tv * fx[j][c2 + 1];
        }
        float2 cv = *(float2*)(cb + hh * 128 + c2);
        cv.x = 1.f / (1.f + expf(-(cv.x + sx * riv)));
        cv.y = 1.f / (1.f + expf(-(cv.y + sy * riv)));
        *(float2*)(cb + hh * 128 + c2) = cv;
    }
}

// ================================================================ host
extern "C" void kernel_launch(void* const* d_in, const int* in_sizes, int n_in,
                              void* d_out, int out_size, void* d_ws, size_t ws_size,
                              hipStream_t stream) {
    const float* x = (const float*)d_in[0];
    const float* eps = (const float*)d_in[1];
    const float* canvas_init = (const float*)d_in[3];
    const float* h_dec_init = (const float*)d_in[4];
    const float* h_enc_init = (const float*)d_in[5];
    const float* W_ih_enc = (const float*)d_in[6];
    const float* b_ih_enc = (const float*)d_in[7];
    const float* W_hh_enc = (const float*)d_in[8];
    const float* b_hh_enc = (const float*)d_in[9];
    const float* W_ih_dec = (const float*)d_in[10];
    const float* b_ih_dec = (const float*)d_in[11];
    const float* W_hh_dec = (const float*)d_in[12];
    const float* b_hh_dec = (const float*)d_in[13];
    const float* W_samp = (const float*)d_in[14];
    const float* b_samp = (const float*)d_in[15];
    const float* W_rattn = (const float*)d_in[16];
    const float* b_rattn = (const float*)d_in[17];
    const float* W_wattn = (const float*)d_in[18];
    const float* b_wattn = (const float*)d_in[19];
    const float* W_writer = (const float*)d_in[20];
    const float* b_writer = (const float*)d_in[21];

    float* out = (float*)d_out;
    float* canvas = out;
    float* out_mu = out + (size_t)BATCH * IMG;
    float* out_lv = out_mu + (size_t)BATCH * TSTEPS * LAT;

    float* ws = (float*)d_ws;
    size_t off = 0;
    auto alloc = [&](size_t n) { float* p = ws + off; off += n; return p; };
    float* c_enc = alloc((size_t)BATCH * HID);
    float* h_dec = alloc((size_t)BATCH * HID);
    float* c_dec = alloc((size_t)BATCH * HID);
    float* gates = alloc((size_t)2 * BATCH * GATES);
    float* WsT = alloc((size_t)HID * 256);
    unsigned short* A_enc = (unsigned short*)alloc((size_t)BATCH * SEC_E);   // B*2*SEC_E shorts
    unsigned short* A_dec = (unsigned short*)alloc((size_t)BATCH * SEC_D);
    unsigned short* Ws_enc = (unsigned short*)alloc((size_t)GATES * SEC_E);
    unsigned short* Ws_dec = (unsigned short*)alloc((size_t)GATES * SEC_D);

    init_canvas<<<BATCH * IMG / 256, 256, 0, stream>>>(canvas, canvas_init);
    init_state<<<BATCH * HID / 256, 256, 0, stream>>>(c_enc, h_dec, c_dec,
                                                      h_enc_init, h_dec_init, A_enc, A_dec);
    prep_wsplit<<<dim3((SEC_E + 255) / 256, GATES), 256, 0, stream>>>(W_ih_enc, ENC_IN, W_hh_enc, HID, Ws_enc, SEC_E);
    prep_wsplit<<<dim3((SEC_D + 255) / 256, GATES), 256, 0, stream>>>(W_ih_dec, LAT, W_hh_dec, HID, Ws_dec, SEC_D);
    prep_wsampT<<<HID * 256 / 256, 256, 0, stream>>>(W_samp, WsT);

    const int ktE = 3 * SEC_E / 64;   // 63
    const int ktD = 3 * SEC_D / 64;   // 30

    for (int t = 0; t < TSTEPS; ++t) {
        read_glimpse_fused<<<BATCH, 512, 0, stream>>>(x, canvas, h_dec, W_rattn, b_rattn, A_enc);
        gemm_bf16x3<<<dim3(BATCH / 64, GATES / 64, 2), 256, 0, stream>>>(
            A_enc, Ws_enc, gates, SEC_E, 0, 32, 32, ktE);
        lstm_enc_samp_z<<<BATCH, 512, 0, stream>>>(
            gates, gates + (size_t)BATCH * GATES, b_ih_enc, b_hh_enc, c_enc, A_enc,
            WsT, b_samp, eps + (size_t)t * BATCH * LAT, A_dec, out_mu, out_lv, t);
        gemm_bf16x3<<<dim3(BATCH / 64, GATES / 64, 2), 256, 0, stream>>>(
            A_dec, Ws_dec, gates, SEC_D, 0, 15, 15, ktD);
        lstm_pw<<<BATCH * HID / 256, 256, 0, stream>>>(gates, gates + (size_t)BATCH * GATES,
                                                       b_ih_dec, b_hh_dec, h_dec, c_dec,
                                                       A_dec, 128, SEC_D);
        if (t < TSTEPS - 1) {
            write_canvas_fused<<<BATCH, 512, 0, stream>>>(canvas, h_dec, W_writer, b_writer,
                                                          W_wattn, b_wattn);
        } else {
            write_final_fused<<<BATCH, 512, 0, stream>>>(canvas, h_dec,
                                                         W_wattn, b_wattn, W_writer, b_writer);
        }
    }
}